// Round 1
// baseline (99.082 us; speedup 1.0000x reference)
//
#include <hip/hip_runtime.h>
#include <math.h>

// Problem constants (fixed by reference setup_inputs)
constexpr int B = 2;
constexpr int N = 4096;   // pred points per batch
constexpr int M = 4096;   // target points per batch
constexpr int L = 512;    // latent dim

constexpr float KL_W = 0.001f;
constexpr float Q_W  = 0.1f;

// pairmin tiling:
//   THREADS=512, QPT=8 -> QC=4096 = ALL queries per block (one x-slice).
//   QPT=8 halves LDS ds_read per pair vs QPT=4 (1 b128 per 32 VALU).
//   DT=32 -> grid (GY=128, GZ=6) = 768 blocks = exactly 3 blocks/CU,
//   8 waves/block -> 24 waves/CU (vs 12 before), single residency generation.
constexpr int THREADS = 512;
constexpr int QPT     = 8;                // queries per thread (strided by THREADS)
constexpr int QC      = THREADS * QPT;    // 4096 queries per block (= N)
constexpr int DT      = 32;               // data-tile points (512 B LDS)
constexpr int GY      = M / DT;           // 128 partial-min slices
constexpr int GZ      = 3 * B;            // 6 -> 768 blocks
constexpr int RB      = 96;               // reduce blocks: 16 per z, 64 threads each

// ws layout:
//   [0)          float  partial[GY][GZ][N]   12.58 MB (every slot written once)
//   [12582912)   double blocksums[RB][2]     1536 B
//   [12584448)   int    ctr                  4 B (last-block-done counter)
constexpr size_t OFF_PARTIAL = 0;
constexpr size_t OFF_BSUMS   = (size_t)GY * GZ * N * 4;
constexpr size_t OFF_CTR     = OFF_BSUMS + (size_t)RB * 2 * 8;

__global__ __launch_bounds__(THREADS) void mgl_pairmin_kernel(
    const float* __restrict__ pred, const float* __restrict__ target,
    float* __restrict__ partial, int* __restrict__ ctr)
{
    __shared__ float4 tile[DT];

    const int tid = threadIdx.x;
    const int z   = blockIdx.y;     // 0..5
    const int dir = z >> 1;
    const int b   = z & 1;

    // zero the reduce kernel's done-counter once per iteration (ws is re-poisoned
    // by the harness each iteration; stream order guarantees this lands before
    // any reduce block's atomicAdd)
    if (blockIdx.x == 0 && z == 0 && tid == 0) *ctr = 0;

    const float* qb; const float* db;
    if (dir == 0)      { qb = pred   + b * N * 3; db = target + b * M * 3; }
    else if (dir == 1) { qb = target + b * M * 3; db = pred   + b * N * 3; }
    else               { qb = pred   + b * N * 3; db = pred   + b * N * 3; }

    const int d0 = blockIdx.x * DT;

    // stage data tile with |t|^2 precomputed (once per point, reused by 4096 queries)
    if (tid < DT) {
        const float* p = db + (size_t)(d0 + tid) * 3;
        float x = p[0], y = p[1], zz = p[2];
        tile[tid] = make_float4(x, y, zz, fmaf(x, x, fmaf(y, y, zz * zz)));
    }

    // QPT=8 strided queries per thread (wave reads 768 B contiguous per k)
    float ax[QPT], ay[QPT], az[QPT], qw[QPT], m[QPT];
    // diagonal bookkeeping: query qk = tid + k*512; its self-pair lives in this
    // tile iff qk-d0 in [0,DT). Since 512 > DT, at most ONE k per thread.
    int kb = -1, jb = 0;
    #pragma unroll
    for (int k = 0; k < QPT; ++k) {
        const int qk = tid + k * THREADS;
        const float* p = qb + (size_t)qk * 3;
        float x = p[0], y = p[1], zz = p[2];
        qw[k] = fmaf(x, x, fmaf(y, y, zz * zz));
        ax[k] = -2.0f * x; ay[k] = -2.0f * y; az[k] = -2.0f * zz;
        m[k]  = 3.402823466e+38f;
        const int j = qk - d0;
        if (dir == 2 && (unsigned)j < (unsigned)DT) { kb = k; jb = j; }
    }

    __syncthreads();

    // clean inner loop for ALL blocks (no diagonal predication): 2 points per
    // step so min(min(m,v0),v1) fuses to v_min3_f32 -> 3.5 VALU/pair
    #pragma unroll 4
    for (int j = 0; j < DT; j += 2) {
        float4 t0 = tile[j];       // wave-uniform address: LDS broadcast, conflict-free
        float4 t1 = tile[j + 1];
        #pragma unroll
        for (int k = 0; k < QPT; ++k) {
            float v0 = fmaf(ax[k], t0.x, fmaf(ay[k], t0.y, fmaf(az[k], t0.z, t0.w)));
            float v1 = fmaf(ax[k], t1.x, fmaf(ay[k], t1.y, fmaf(az[k], t1.z, t1.w)));
            m[k] = fminf(fminf(m[k], v0), v1);
        }
    }

    // diagonal repair: the clean loop polluted m[kb] with the self-pair
    // (value -|q|^2 -> 0 after +qw). min is lossy, so RECOMPUTE that one k-row
    // excluding jb. Only DT=32 threads of 512 per pp-block enter; dir 0/1
    // blocks skip uniformly. Static register indexing only (no scratch).
    if (kb >= 0) {
        float bx = 0.f, by = 0.f, bz = 0.f;
        #pragma unroll
        for (int k = 0; k < QPT; ++k)
            if (k == kb) { bx = ax[k]; by = ay[k]; bz = az[k]; }
        float mm = 3.402823466e+38f;
        #pragma unroll 4
        for (int j = 0; j < DT; ++j) {
            float4 t = tile[j];
            float v = fmaf(bx, t.x, fmaf(by, t.y, fmaf(bz, t.z, t.w)));
            mm = (j == jb) ? mm : fminf(mm, v);   // ref masks diag with +1e6; exclusion is equivalent
        }
        #pragma unroll
        for (int k = 0; k < QPT; ++k)
            if (k == kb) m[k] = mm;
    }

    // add |q|^2 (commutes with min); clamp tiny negative from cancellation.
    // every (gy,z,q) slot written exactly once -> plain coalesced stores.
    float* slice = partial + ((size_t)blockIdx.x * GZ + z) * N;
    #pragma unroll
    for (int k = 0; k < QPT; ++k)
        slice[tid + k * THREADS] = fmaxf(m[k] + qw[k], 0.0f);
}

// Fused reduce+final: 96 blocks x 64 threads (1 wave each), 16 blocks per z,
// each thread owns one float4 query-group and min-scans the GY=128 slices.
// Last block to finish (device-scope atomic) computes KL + the final scalars.
__global__ __launch_bounds__(64) void mgl_reduce_final_kernel(
    const float* __restrict__ partial, const float* __restrict__ mu,
    const float* __restrict__ logvar, double* __restrict__ blocksums,
    int* __restrict__ ctr, float* __restrict__ out)
{
    const int tid = threadIdx.x;           // 0..63
    const int bid = blockIdx.x;            // 0..95
    const int z   = bid >> 4;              // 0..5
    const int idx = ((bid & 15) << 6) | tid;   // 0..1023 float4-groups

    constexpr size_t SL = (size_t)GZ * N / 4;  // float4 stride between gy slices
    const float4* p = (const float4*)(partial + (size_t)z * N) + idx;

    float4 mn = p[0];
    #pragma unroll 8
    for (int gy = 1; gy < GY; ++gy) {
        float4 v = p[(size_t)gy * SL];
        mn.x = fminf(mn.x, v.x); mn.y = fminf(mn.y, v.y);
        mn.z = fminf(mn.z, v.z); mn.w = fminf(mn.w, v.w);
    }

    double s  = (double)mn.x + (double)mn.y + (double)mn.z + (double)mn.w;
    double ss = (double)mn.x * mn.x + (double)mn.y * mn.y
              + (double)mn.z * mn.z + (double)mn.w * mn.w;

    #pragma unroll
    for (int off = 32; off > 0; off >>= 1) {
        s  += __shfl_down(s,  off, 64);
        ss += __shfl_down(ss, off, 64);
    }

    int lastf = 0;
    if (tid == 0) {
        blocksums[bid * 2 + 0] = s;
        blocksums[bid * 2 + 1] = ss;
        __threadfence();                          // release our blocksums
        lastf = (atomicAdd(ctr, 1) == RB - 1);
    }
    lastf = __shfl(lastf, 0, 64);                 // wave-uniform broadcast
    if (!lastf) return;
    __threadfence();                              // acquire others' blocksums

    // KL over B*L = 1024 elements, 16 per thread, coalesced
    double skl = 0.0;
    #pragma unroll
    for (int k = 0; k < (B * L) / 64; ++k) {
        const int i = (k << 6) | tid;
        double mm = (double)mu[i];
        double lv = (double)logvar[i];
        skl += 1.0 + lv - mm * mm - exp(lv);
    }
    #pragma unroll
    for (int off = 32; off > 0; off >>= 1)
        skl += __shfl_down(skl, off, 64);

    if (tid == 0) {
        double sPT[B] = {0.0, 0.0}, sTP[B] = {0.0, 0.0};
        double sPP[B] = {0.0, 0.0}, ssPP[B] = {0.0, 0.0};
        for (int i = 0; i < RB; ++i) {
            const int zz  = i >> 4;
            const int dr  = zz >> 1;
            const int bb  = zz & 1;
            double s_  = blocksums[i * 2 + 0];
            double ss_ = blocksums[i * 2 + 1];
            if (dr == 0)      sPT[bb] += s_;
            else if (dr == 1) sTP[bb] += s_;
            else            { sPP[bb] += s_; ssPP[bb] += ss_; }
        }

        double cd = 0.0;
        #pragma unroll
        for (int bb = 0; bb < B; ++bb)
            cd += sPT[bb] / (double)N + sTP[bb] / (double)M;
        cd /= (double)B;

        double density = 0.0;
        #pragma unroll
        for (int bb = 0; bb < B; ++bb) {
            double var = (ssPP[bb] - sPP[bb] * sPP[bb] / (double)N) / (double)(N - 1);
            density += sqrt(var > 0.0 ? var : 0.0);
        }
        density /= (double)B;

        double kl = -0.5 * skl / (double)(B * L);

        double total = cd + (double)KL_W * kl + (double)Q_W * density;
        out[0] = (float)total;
        out[1] = (float)cd;
        out[2] = (float)kl;
        out[3] = (float)density;
    }
}

extern "C" void kernel_launch(void* const* d_in, const int* in_sizes, int n_in,
                              void* d_out, int out_size, void* d_ws, size_t ws_size,
                              hipStream_t stream) {
    const float* pred   = (const float*)d_in[0];
    const float* target = (const float*)d_in[1];
    const float* mu     = (const float*)d_in[2];
    const float* logvar = (const float*)d_in[3];
    float* out = (float*)d_out;

    char* ws = (char*)d_ws;
    float*  partial   = (float*)(ws + OFF_PARTIAL);
    double* blocksums = (double*)(ws + OFF_BSUMS);
    int*    ctr       = (int*)(ws + OFF_CTR);

    mgl_pairmin_kernel<<<dim3(GY, GZ), THREADS, 0, stream>>>(pred, target, partial, ctr);
    mgl_reduce_final_kernel<<<RB, 64, 0, stream>>>(partial, mu, logvar, blocksums, ctr, out);
}

// Round 2
// 75.876 us; speedup vs baseline: 1.3059x; 1.3059x over previous
//
#include <hip/hip_runtime.h>
#include <math.h>

// Problem constants (fixed by reference setup_inputs)
constexpr int B = 2;
constexpr int N = 4096;   // pred points per batch
constexpr int M = 4096;   // target points per batch
constexpr int L = 512;    // latent dim

constexpr float KL_W = 0.001f;
constexpr float Q_W  = 0.1f;

// pairmin tiling (PROVEN 75.1us topology — do not change grid shape):
// QPT=4 halves broadcast ds_read per pair; DT=128 keeps the grid at
// 768 blocks = exactly 3 blocks/CU (384 blocks = imbalance, R8).
constexpr int THREADS = 256;
constexpr int QPT     = 4;               // queries per thread (strided by THREADS)
constexpr int QC      = THREADS * QPT;   // 1024 queries per block
constexpr int DT      = 128;             // data-tile points (2 KB LDS)
constexpr int GX      = N / QC;          // 4
constexpr int GY      = M / DT;          // 32 partial-min slices
constexpr int GZ      = 3 * B;           // 6  -> 768 blocks, 3 blocks/CU balanced
constexpr int RB      = 24;              // reduce blocks (4 per z, 256 threads)

// ws layout:
//   [0)        float  partial[GY][GZ][N]   3 MB  (every slot written once)
//   [3145728)  double blocksums[RB][2]     384 B
//   [3146112)  int    ctr                  4 B   (last-block-done counter)
constexpr size_t OFF_PARTIAL = 0;
constexpr size_t OFF_BSUMS   = (size_t)GY * GZ * N * 4;
constexpr size_t OFF_CTR     = OFF_BSUMS + (size_t)RB * 2 * 8;

__global__ __launch_bounds__(THREADS) void mgl_pairmin_kernel(
    const float* __restrict__ pred, const float* __restrict__ target,
    float* __restrict__ partial, int* __restrict__ ctr)
{
    __shared__ float4 tile[DT];

    const int z   = blockIdx.z;     // 0..5
    const int dir = z >> 1;
    const int b   = z & 1;

    // zero the reduce kernel's done-counter once per iteration (ws is
    // re-poisoned each iteration; stream order + kernel-boundary writeback
    // make this visible to the dependent reduce launch — validated R1)
    if (blockIdx.x == 0 && blockIdx.y == 0 && z == 0 && threadIdx.x == 0)
        *ctr = 0;

    const float* qb; const float* db;
    if (dir == 0)      { qb = pred   + b * N * 3; db = target + b * M * 3; }
    else if (dir == 1) { qb = target + b * M * 3; db = pred   + b * N * 3; }
    else               { qb = pred   + b * N * 3; db = pred   + b * N * 3; }

    const int q0 = blockIdx.x * QC;
    const int d0 = blockIdx.y * DT;

    // stage data tile: compute |t|^2 during staging (once per point, reused by 1024 queries)
    if (threadIdx.x < DT) {
        const float* p = db + (size_t)(d0 + threadIdx.x) * 3;
        float x = p[0], y = p[1], zz = p[2];
        tile[threadIdx.x] = make_float4(x, y, zz, fmaf(x, x, fmaf(y, y, zz * zz)));
    }

    // QPT strided queries per thread (coalesced 12 B/lane wave spans)
    int   qi[QPT];
    float ax[QPT], ay[QPT], az[QPT], qw[QPT], m[QPT];
    #pragma unroll
    for (int k = 0; k < QPT; ++k) {
        qi[k] = q0 + threadIdx.x + k * THREADS;
        float x = qb[qi[k] * 3 + 0], y = qb[qi[k] * 3 + 1], zz = qb[qi[k] * 3 + 2];
        qw[k] = fmaf(x, x, fmaf(y, y, zz * zz));
        ax[k] = -2.0f * x; ay[k] = -2.0f * y; az[k] = -2.0f * zz;
        m[k]  = 3.402823466e+38f;
    }

    __syncthreads();

    // diagonal can only appear in dir-2 blocks whose d-tile overlaps their q-range
    const bool diag = (dir == 2) && (d0 < q0 + QC) && (d0 + DT > q0);

    if (!diag) {
        // 2 tile points per step: fminf(fminf(m,v0),v1) fuses to v_min3_f32
        // -> 3.5 VALU/pair instead of 4 (the only inner-loop change vs R0)
        #pragma unroll 4
        for (int j = 0; j < DT; j += 2) {
            float4 t0 = tile[j];       // wave-uniform address: LDS broadcast, conflict-free
            float4 t1 = tile[j + 1];
            #pragma unroll
            for (int k = 0; k < QPT; ++k) {
                float v0 = fmaf(ax[k], t0.x, fmaf(ay[k], t0.y, fmaf(az[k], t0.z, t0.w)));
                float v1 = fmaf(ax[k], t1.x, fmaf(ay[k], t1.y, fmaf(az[k], t1.z, t1.w)));
                m[k] = fminf(fminf(m[k], v0), v1);
            }
        }
    } else {
        #pragma unroll 8
        for (int j = 0; j < DT; ++j) {
            float4 t = tile[j];
            const int dj = d0 + j;
            #pragma unroll
            for (int k = 0; k < QPT; ++k) {
                float v = fmaf(ax[k], t.x, fmaf(ay[k], t.y, fmaf(az[k], t.z, t.w)));
                v = (dj == qi[k]) ? 3.402823466e+38f : v;   // exclude diagonal (ref masks +1e6)
                m[k] = fminf(m[k], v);
            }
        }
    }

    // add |q|^2 (constant per query, commutes with min); clamp tiny negative from cancellation
    // plain coalesced stores; every (gy,z,qi) slot written exactly once -> no init, no atomics
    float* slice = partial + ((size_t)blockIdx.y * GZ + z) * N;
    #pragma unroll
    for (int k = 0; k < QPT; ++k)
        slice[qi[k]] = fmaxf(m[k] + qw[k], 0.0f);
}

// Fused reduce+final: 24 blocks x 256 threads (R0's proven reduce topology),
// block b handles z = b>>2, queries [(b&3)*1024, +1024) grouped by 4.
// Last block to finish (device-scope atomic) also computes KL + final scalars,
// saving one dependent launch.
__global__ __launch_bounds__(256) void mgl_reduce_final_kernel(
    const float* __restrict__ partial, const float* __restrict__ mu,
    const float* __restrict__ logvar, double* __restrict__ blocksums,
    int* __restrict__ ctr, float* __restrict__ out)
{
    const int tid = threadIdx.x;
    const int bid = blockIdx.x;            // 0..23
    const int z   = bid >> 2;              // 0..5
    const int q4  = ((bid & 3) * 256 + tid) * 4;

    const float4* p = (const float4*)(partial + (size_t)z * N + q4);
    float4 mn = p[0];
    #pragma unroll
    for (int gy = 1; gy < GY; ++gy) {
        float4 v = p[(size_t)gy * (GZ * N / 4)];
        mn.x = fminf(mn.x, v.x); mn.y = fminf(mn.y, v.y);
        mn.z = fminf(mn.z, v.z); mn.w = fminf(mn.w, v.w);
    }

    double s  = (double)mn.x + (double)mn.y + (double)mn.z + (double)mn.w;
    double ss = (double)mn.x * mn.x + (double)mn.y * mn.y
              + (double)mn.z * mn.z + (double)mn.w * mn.w;

    // wave64 shuffle reduce, then cross-wave via LDS
    #pragma unroll
    for (int off = 32; off > 0; off >>= 1) {
        s  += __shfl_down(s,  off, 64);
        ss += __shfl_down(ss, off, 64);
    }
    __shared__ double wred[4][2];
    const int wid  = tid >> 6;
    const int lane = tid & 63;
    if (lane == 0) { wred[wid][0] = s; wred[wid][1] = ss; }
    __syncthreads();

    __shared__ int sflag;
    if (tid == 0) {
        double ts  = wred[0][0] + wred[1][0] + wred[2][0] + wred[3][0];
        double tss = wred[0][1] + wred[1][1] + wred[2][1] + wred[3][1];
        blocksums[bid * 2 + 0] = ts;
        blocksums[bid * 2 + 1] = tss;
        __threadfence();                           // release our blocksums
        sflag = (atomicAdd(ctr, 1) == RB - 1);     // device-scope by default (G12)
    }
    __syncthreads();
    if (!sflag) return;
    __threadfence();                               // acquire others' blocksums

    // ---- last block only: KL over B*L = 1024 elements, 4 per thread ----
    double skl = 0.0;
    #pragma unroll
    for (int k = 0; k < 4; ++k) {
        int i = tid * 4 + k;
        double mm = (double)mu[i];
        double lv = (double)logvar[i];
        skl += 1.0 + lv - mm * mm - exp(lv);
    }
    #pragma unroll
    for (int off = 32; off > 0; off >>= 1)
        skl += __shfl_down(skl, off, 64);

    __shared__ double wkl[4];
    if (lane == 0) wkl[wid] = skl;
    __syncthreads();

    if (tid == 0) {
        double tkl = wkl[0] + wkl[1] + wkl[2] + wkl[3];

        double sPT[B] = {0.0, 0.0}, sTP[B] = {0.0, 0.0};
        double sPP[B] = {0.0, 0.0}, ssPP[B] = {0.0, 0.0};
        for (int i = 0; i < RB; ++i) {
            const int zz  = i >> 2;
            const int dr  = zz >> 1;
            const int bb  = zz & 1;
            double s_  = blocksums[i * 2 + 0];
            double ss_ = blocksums[i * 2 + 1];
            if (dr == 0)      sPT[bb] += s_;
            else if (dr == 1) sTP[bb] += s_;
            else            { sPP[bb] += s_; ssPP[bb] += ss_; }
        }

        double cd = 0.0;
        #pragma unroll
        for (int bb = 0; bb < B; ++bb)
            cd += sPT[bb] / (double)N + sTP[bb] / (double)M;
        cd /= (double)B;

        double density = 0.0;
        #pragma unroll
        for (int bb = 0; bb < B; ++bb) {
            double var = (ssPP[bb] - sPP[bb] * sPP[bb] / (double)N) / (double)(N - 1);
            density += sqrt(var > 0.0 ? var : 0.0);
        }
        density /= (double)B;

        double kl = -0.5 * tkl / (double)(B * L);

        double total = cd + (double)KL_W * kl + (double)Q_W * density;
        out[0] = (float)total;
        out[1] = (float)cd;
        out[2] = (float)kl;
        out[3] = (float)density;
    }
}

extern "C" void kernel_launch(void* const* d_in, const int* in_sizes, int n_in,
                              void* d_out, int out_size, void* d_ws, size_t ws_size,
                              hipStream_t stream) {
    const float* pred   = (const float*)d_in[0];
    const float* target = (const float*)d_in[1];
    const float* mu     = (const float*)d_in[2];
    const float* logvar = (const float*)d_in[3];
    float* out = (float*)d_out;

    char* ws = (char*)d_ws;
    float*  partial   = (float*)(ws + OFF_PARTIAL);
    double* blocksums = (double*)(ws + OFF_BSUMS);
    int*    ctr       = (int*)(ws + OFF_CTR);

    mgl_pairmin_kernel<<<dim3(GX, GY, GZ), THREADS, 0, stream>>>(pred, target, partial, ctr);
    mgl_reduce_final_kernel<<<RB, 256, 0, stream>>>(partial, mu, logvar, blocksums, ctr, out);
}